// Round 11
// baseline (221.007 us; speedup 1.0000x reference)
//
#include <hip/hip_runtime.h>
#include <hip/hip_bf16.h>
#include <math.h>

typedef float  f4 __attribute__((ext_vector_type(4)));
typedef short  s8 __attribute__((ext_vector_type(8)));
typedef short  s4 __attribute__((ext_vector_type(4)));
typedef int    i2 __attribute__((ext_vector_type(2)));

#define NV 28
#define NB 32768
#define BN_EPS 1e-5f
#define NSLOT 434   // 28 col-sums + 406 upper-tri Gram products

// ---- workspace layout (float indices unless noted) ----
#define SUM2_OFF   0        // 1792
#define SSQ2_OFF   1792     // 1792
#define BIAS1_OFF  3584     // 1792 -> 5376
#define PART_OFF   9472     // 256*434 -> 120576
#define BF_BASE_F  120640   // bf16 region; byte 482560 (16B aligned)
#define W2B_OFF_S  57344    // short offset of W2 bf16
#define XBF_OFF_S  172032   // short offset of padded bf16 X [32768][32]
#define H2_BYTE_OFF 2924544ull
#define H2_BYTES    117440512ull      // 28*32768*64*2

// fast gelu via hw exp2/rcp; max abs err ~5e-4
__device__ __forceinline__ float gelu_f(float x) {
    float x2 = x * x;
    float z  = x * __builtin_fmaf(x2, -0.10294324f, -2.3022082f);
    float t  = __builtin_amdgcn_exp2f(z);
    return x * __builtin_amdgcn_rcpf(1.0f + t);
}
// cheap round-to-nearest-even f32->bf16 (finite inputs)
__device__ __forceinline__ unsigned short f2bf(float x) {
    unsigned u = __builtin_bit_cast(unsigned, x);
    return (unsigned short)((u + 0x7fffu + ((u >> 16) & 1u)) >> 16);
}
__device__ __forceinline__ float bf2f(short s) {
    return __builtin_bit_cast(float, ((int)(unsigned short)s) << 16);
}
// pack two f32 -> two bf16 (round-nearest, ties-up) in 3 VALU ops via v_perm
__device__ __forceinline__ int bfpack(float a, float b) {
    unsigned ua = __builtin_bit_cast(unsigned, a) + 0x8000u;
    unsigned ub = __builtin_bit_cast(unsigned, b) + 0x8000u;
    return __builtin_amdgcn_perm(ub, ua, 0x07060302);  // lo16=bf16(a), hi16=bf16(b)
}
// sum across the 16 lanes of a DPP row; all lanes get the total
__device__ __forceinline__ float row16_sum(float v) {
    int x;
    x = __builtin_amdgcn_update_dpp(0, __builtin_bit_cast(int, v), 0xB1, 0xF, 0xF, true);
    v += __builtin_bit_cast(float, x);
    x = __builtin_amdgcn_update_dpp(0, __builtin_bit_cast(int, v), 0x4E, 0xF, 0xF, true);
    v += __builtin_bit_cast(float, x);
    x = __builtin_amdgcn_update_dpp(0, __builtin_bit_cast(int, v), 0x124, 0xF, 0xF, true);
    v += __builtin_bit_cast(float, x);
    x = __builtin_amdgcn_update_dpp(0, __builtin_bit_cast(int, v), 0x128, 0xF, 0xF, true);
    v += __builtin_bit_cast(float, x);
    return v;
}
// sum across a 4-lane quad; all 4 lanes get the total
__device__ __forceinline__ float quad4_sum(float v) {
    int x;
    x = __builtin_amdgcn_update_dpp(0, __builtin_bit_cast(int, v), 0xB1, 0xF, 0xF, true);
    v += __builtin_bit_cast(float, x);
    x = __builtin_amdgcn_update_dpp(0, __builtin_bit_cast(int, v), 0x4E, 0xF, 0xF, true);
    v += __builtin_bit_cast(float, x);
    return v;
}

// ------ X stats partials (upper-tri only) + bf16 pre-conversion of X -----
__global__ __launch_bounds__(256) void k_xstats(const float* __restrict__ X,
                                                float* __restrict__ ws) {
    __shared__ float sx[128 * 28];
    const int tid = threadIdx.x;
    const int rowbase = blockIdx.x * 128;
    {
        const f4* src = (const f4*)(X + (size_t)rowbase * 28);
        f4* dst = (f4*)sx;
        for (int i = tid; i < 128 * 28 / 4; i += 256) dst[i] = src[i];
    }
    __syncthreads();
    // bf16 X, padded to 32 cols (cols 28..31 zero)
    int* xb = (int*)((short*)(ws + BF_BASE_F) + XBF_OFF_S);
    for (int j = tid; j < 128 * 16; j += 256) {
        int row = j >> 4, cc = j & 15;
        float lo = (2 * cc     < 28) ? sx[row * 28 + 2 * cc]     : 0.0f;
        float hi = (2 * cc + 1 < 28) ? sx[row * 28 + 2 * cc + 1] : 0.0f;
        xb[(size_t)(rowbase + row) * 16 + cc] = (int)f2bf(lo) | ((int)f2bf(hi) << 16);
    }
    // slots: 0..27 col sums, 28.. upper-tri products (d<=e)
    for (int s = tid; s < NSLOT; s += 256) {
        float a = 0.0f;
        if (s < 28) {
            for (int r = 0; r < 128; ++r) a += sx[r * 28 + s];
        } else {
            int p = s - 28, d = 0, rem = 28;
            while (p >= rem) { p -= rem; ++d; --rem; }
            int e = d + p;
            for (int r = 0; r < 128; ++r)
                a = __builtin_fmaf(sx[r * 28 + d], sx[r * 28 + e], a);
        }
        ws[PART_OFF + blockIdx.x * NSLOT + s] = a;
    }
}

// ------ fold: reduce partials; sigmoid mask; analytic BN1 -> bf16 weights -
__global__ __launch_bounds__(256) void k_fold1(const float* __restrict__ Wlog,
                                               const float* __restrict__ W1,
                                               const float* __restrict__ g1,
                                               const float* __restrict__ be1,
                                               const float* __restrict__ W2,
                                               float* __restrict__ ws,
                                               float* __restrict__ out_w) {
    __shared__ float sstat[NSLOT];
    __shared__ float mu[28], wrow[28];
    __shared__ float C[784];
    __shared__ float w1e_s[64 * 28];
    const int n = blockIdx.x, t = threadIdx.x;

    // reduce the 256 xstats partials (strided; 16-deep load pipelining)
    for (int s = t; s < NSLOT; s += 256) {
        float a = 0.0f;
#pragma unroll 16
        for (int p = 0; p < 256; ++p) a += ws[PART_OFF + p * NSLOT + s];
        sstat[s] = a;
    }
    if (t < 64) {   // zero pass-1 stat accumulators for this mechanism
        ws[SUM2_OFF + n * 64 + t] = 0.0f;
        ws[SSQ2_OFF + n * 64 + t] = 0.0f;
    }
    __syncthreads();

    if (t < 28) {
        mu[t] = sstat[t] * (1.0f / 32768.0f);
        float w = 1.0f / (1.0f + expf(-Wlog[n * 28 + t]));
        if (t == n) w = 0.0f;
        wrow[t] = w;
        out_w[n * 28 + t] = w;          // second output: adjacency W
    }
    __syncthreads();
    // full covariance from upper-tri Gram: C = G/N - mu mu^T
    for (int i = t; i < 784; i += 256) {
        int d = i / 28, e = i % 28;
        int lo = d < e ? d : e, hi = d < e ? e : d;
        int idx = 28 + lo * 28 - (lo * (lo - 1)) / 2 + (hi - lo);
        C[i] = sstat[idx] * (1.0f / 32768.0f) - mu[d] * mu[e];
    }
    // masked first-layer weights for all 64 units (coalesced W1 reads)
    for (int i = t; i < 1792; i += 256)
        w1e_s[i] = W1[(size_t)n * 1792 + i] * wrow[i % 28];
    __syncthreads();

    const int h = t >> 2, j = t & 3;    // 4 lanes per hidden unit (one quad)
    const float* we = &w1e_s[h * 28];
    float var_p = 0.0f, dot_p = 0.0f;
#pragma unroll
    for (int k = 0; k < 7; ++k) {
        int d = 7 * j + k;
        float inner = 0.0f;
#pragma unroll
        for (int e = 0; e < 28; ++e) inner = __builtin_fmaf(C[d * 28 + e], we[e], inner);
        float wd = we[d];
        var_p = __builtin_fmaf(inner, wd, var_p);
        dot_p = __builtin_fmaf(wd, mu[d], dot_p);
    }
    float var  = quad4_sum(var_p);
    float dotm = quad4_sum(dot_p);
    float scale = g1[n * 64 + h] * rsqrtf(fmaxf(var, 0.0f) + BN_EPS);
    if (j == 0)
        ws[BIAS1_OFF + n * 64 + h] = be1[n * 64 + h] - dotm * scale;  // b1 cancels in BN

    short* bfbase = (short*)(ws + BF_BASE_F);
    {   // folded W1 bf16, padded to 32: lane j packs d in [8j, 8j+8)
        short* w1f = bfbase + (size_t)(n * 64 + h) * 32;
        s8 pk;
#pragma unroll
        for (int k = 0; k < 8; ++k) {
            int d = 8 * j + k;
            pk[k] = (short)f2bf(d < 28 ? we[d] * scale : 0.0f);
        }
        *(s8*)&w1f[8 * j] = pk;
    }
    {   // W2 -> bf16: 16 elements per thread, 16-B stores
        const float* w2src = W2 + (size_t)n * 4096 + t * 16;
        short* w2d = bfbase + W2B_OFF_S + (size_t)n * 4096 + t * 16;
        s8 a, b;
#pragma unroll
        for (int k = 0; k < 8; ++k) a[k] = (short)f2bf(w2src[k]);
#pragma unroll
        for (int k = 0; k < 8; ++k) b[k] = (short)f2bf(w2src[8 + k]);
        *(s8*)&w2d[0] = a;
        *(s8*)&w2d[8] = b;
    }
}

// ------ pass 1: GEMM1+gelu+GEMM2 (dual chains), reg stats, bf16 h2 store -
// proven config: launch_bounds(256,4), LDS-reduction epilogue; 512 rows/blk.
// Tighter bounds (256,5)/(256,6) spill (r7/r8: WRITE_SIZE 204-242 MB).
template <bool STORE>
__global__ __launch_bounds__(256, 4) void k_pass1(float* __restrict__ ws,
                                                  short* __restrict__ h2buf) {
    __shared__ __align__(16) short sW1[64 * 40];
    __shared__ __align__(16) short sW2[64 * 72];
    __shared__ __align__(16) short sA1[8 * 16 * 72];     // 2 tiles per wave
    __shared__ float sP1[4][64], sP2[4][64];

    const int n = blockIdx.x >> 6;
    const int blk = blockIdx.x & 63;
    const int tid = threadIdx.x;
    const int wave = tid >> 6;
    const int lane = tid & 63;
    const int m = lane & 15;
    const int q = lane >> 4;

    const short* bfbase = (const short*)(ws + BF_BASE_F);
    const short* w1g = bfbase + (size_t)n * 64 * 32;
    const short* w2g = bfbase + W2B_OFF_S + (size_t)n * 64 * 64;
    const short* xbf = bfbase + XBF_OFF_S;
    {
        int r = tid >> 2, c = tid & 3;
        *(s8*)&sW1[r * 40 + c * 8] = *(const s8*)&w1g[r * 32 + c * 8];
#pragma unroll
        for (int k = 0; k < 2; ++k) {
            int i2x = tid + k * 256;
            int r2 = i2x >> 3, c2 = i2x & 7;
            *(s8*)&sW2[r2 * 72 + c2 * 8] = *(const s8*)&w2g[r2 * 64 + c2 * 8];
        }
    }
    __syncthreads();

    // lane-constant bias fragments hoisted (16 VGPRs; ample headroom at bound 4)
    const float* bias1 = ws + BIAS1_OFF + n * 64;
    f4 biasv[4];
#pragma unroll
    for (int t = 0; t < 4; ++t) biasv[t] = *(const f4*)&bias1[16 * t + 4 * q];

    short* myA1a = &sA1[(wave * 2 + 0) * 16 * 72];
    short* myA1b = &sA1[(wave * 2 + 1) * 16 * 72];
    float s1[16], s2v[16];
#pragma unroll
    for (int i = 0; i < 16; ++i) { s1[i] = 0.0f; s2v[i] = 0.0f; }

#pragma unroll
    for (int it = 0; it < 4; ++it) {
        const int row0 = blk * 512 + it * 128 + wave * 32;
        s8 xfa = *(const s8*)&xbf[(size_t)(row0 + m) * 32 + 8 * q];
        s8 xfb = *(const s8*)&xbf[(size_t)(row0 + 16 + m) * 32 + 8 * q];

        f4 acc1a[4], acc1b[4];
#pragma unroll
        for (int t = 0; t < 4; ++t) {
            s8 wf = *(const s8*)&sW1[(16 * t + m) * 40 + q * 8];
            acc1a[t] = __builtin_amdgcn_mfma_f32_16x16x32_bf16(wf, xfa, (f4){0.f, 0.f, 0.f, 0.f}, 0, 0, 0);
            acc1b[t] = __builtin_amdgcn_mfma_f32_16x16x32_bf16(wf, xfb, (f4){0.f, 0.f, 0.f, 0.f}, 0, 0, 0);
        }
#pragma unroll
        for (int t = 0; t < 4; ++t) {
            float ga0 = gelu_f(acc1a[t][0] + biasv[t][0]);
            float ga1 = gelu_f(acc1a[t][1] + biasv[t][1]);
            float ga2 = gelu_f(acc1a[t][2] + biasv[t][2]);
            float ga3 = gelu_f(acc1a[t][3] + biasv[t][3]);
            float gb0 = gelu_f(acc1b[t][0] + biasv[t][0]);
            float gb1 = gelu_f(acc1b[t][1] + biasv[t][1]);
            float gb2 = gelu_f(acc1b[t][2] + biasv[t][2]);
            float gb3 = gelu_f(acc1b[t][3] + biasv[t][3]);
            i2 pa = (i2){bfpack(ga0, ga1), bfpack(ga2, ga3)};
            i2 pb = (i2){bfpack(gb0, gb1), bfpack(gb2, gb3)};
            *(i2*)&myA1a[m * 72 + 16 * t + 4 * q] = pa;
            *(i2*)&myA1b[m * 72 + 16 * t + 4 * q] = pb;
        }
        // in-wave LDS ordering only; sA1 tiles are wave-private
        s8 af0a = *(const s8*)&myA1a[m * 72 + 8 * q];
        s8 af1a = *(const s8*)&myA1a[m * 72 + 32 + 8 * q];
        s8 af0b = *(const s8*)&myA1b[m * 72 + 8 * q];
        s8 af1b = *(const s8*)&myA1b[m * 72 + 32 + 8 * q];
        short* hpA = STORE ? (h2buf + ((size_t)n * NB + row0 + m) * 64) : nullptr;
        short* hpB = STORE ? (h2buf + ((size_t)n * NB + row0 + 16 + m) * 64) : nullptr;
#pragma unroll
        for (int u = 0; u < 4; ++u) {
            s8 w0 = *(const s8*)&sW2[(16 * u + m) * 72 + 8 * q];
            s8 w1 = *(const s8*)&sW2[(16 * u + m) * 72 + 32 + 8 * q];
            f4 aa = (f4){0.f, 0.f, 0.f, 0.f};
            f4 ab = (f4){0.f, 0.f, 0.f, 0.f};
            aa = __builtin_amdgcn_mfma_f32_16x16x32_bf16(w0, af0a, aa, 0, 0, 0);
            ab = __builtin_amdgcn_mfma_f32_16x16x32_bf16(w0, af0b, ab, 0, 0, 0);
            aa = __builtin_amdgcn_mfma_f32_16x16x32_bf16(w1, af1a, aa, 0, 0, 0);
            ab = __builtin_amdgcn_mfma_f32_16x16x32_bf16(w1, af1b, ab, 0, 0, 0);
            if (STORE) {
                i2 ha = (i2){bfpack(aa[0], aa[1]), bfpack(aa[2], aa[3])};
                i2 hb = (i2){bfpack(ab[0], ab[1]), bfpack(ab[2], ab[3])};
                *(i2*)&hpA[16 * u + 4 * q] = ha;
                *(i2*)&hpB[16 * u + 4 * q] = hb;
            }
#pragma unroll
            for (int r = 0; r < 4; ++r) {
                s1[u * 4 + r]  += aa[r] + ab[r];
                s2v[u * 4 + r] = __builtin_fmaf(aa[r], aa[r], s2v[u * 4 + r]);
                s2v[u * 4 + r] = __builtin_fmaf(ab[r], ab[r], s2v[u * 4 + r]);
            }
        }
    }
    // block-level reduction via LDS (short live ranges; no spill)
#pragma unroll
    for (int u = 0; u < 4; ++u) {
#pragma unroll
        for (int r = 0; r < 4; ++r) {
            float t1 = row16_sum(s1[u * 4 + r]);
            float t2 = row16_sum(s2v[u * 4 + r]);
            if (m == 0) {
                sP1[wave][16 * u + 4 * q + r] = t1;
                sP2[wave][16 * u + 4 * q + r] = t2;
            }
        }
    }
    __syncthreads();
    if (tid < 64) {
        float a = sP1[0][tid] + sP1[1][tid] + sP1[2][tid] + sP1[3][tid];
        float b = sP2[0][tid] + sP2[1][tid] + sP2[2][tid] + sP2[3][tid];
        atomicAdd(&ws[SUM2_OFF + n * 64 + tid], a);
        atomicAdd(&ws[SSQ2_OFF + n * 64 + tid], b);
    }
}

// ------ pass 2 (stored h2, coalesced): BN2+gelu+GEMM3 -> X_hat -----------
// 8 lanes per row: wave loads 1 KB contiguous; 3-step shuffle reduce.
__global__ __launch_bounds__(256) void k_pass2c(const float* __restrict__ g2,
                                                const float* __restrict__ be2,
                                                const float* __restrict__ W3,
                                                const float* __restrict__ b3,
                                                const float* __restrict__ ws,
                                                const short* __restrict__ h2buf,
                                                float* __restrict__ out) {
    __shared__ float sSc[64], sSh[64], sW3v[64];
    const int n = blockIdx.x >> 7;
    const int rbase = (blockIdx.x & 127) * 256;
    const int tid = threadIdx.x;
    if (tid < 64) {
        float mean = ws[SUM2_OFF + n * 64 + tid] * (1.0f / 32768.0f);
        float var  = ws[SSQ2_OFF + n * 64 + tid] * (1.0f / 32768.0f) - mean * mean;
        float sc = g2[n * 64 + tid] * rsqrtf(fmaxf(var, 0.0f) + BN_EPS);
        sSc[tid]  = sc;
        sSh[tid]  = be2[n * 64 + tid] - mean * sc;
        sW3v[tid] = W3[n * 64 + tid];
    }
    __syncthreads();
    const int wave = tid >> 6;
    const int lane = tid & 63;
    const int rr = lane >> 3;          // row within 8-row group
    const int cc = lane & 7;           // 8-feature chunk within row
    // per-lane feature params in registers (shared across all rows)
    f4 scA = *(const f4*)&sSc[cc * 8],     scB = *(const f4*)&sSc[cc * 8 + 4];
    f4 shA = *(const f4*)&sSh[cc * 8],     shB = *(const f4*)&sSh[cc * 8 + 4];
    f4 w3A = *(const f4*)&sW3v[cc * 8],    w3B = *(const f4*)&sW3v[cc * 8 + 4];
    const float b3n = b3[n];
#pragma unroll
    for (int it = 0; it < 8; ++it) {
        const int row = rbase + wave * 64 + it * 8 + rr;
        s8 hv = *(const s8*)(h2buf + ((size_t)n * NB + row) * 64 + cc * 8);
        float p = 0.0f;
#pragma unroll
        for (int j = 0; j < 4; ++j) {
            float v = __builtin_fmaf(bf2f(hv[j]), scA[j], shA[j]);
            p = __builtin_fmaf(gelu_f(v), w3A[j], p);
        }
#pragma unroll
        for (int j = 0; j < 4; ++j) {
            float v = __builtin_fmaf(bf2f(hv[4 + j]), scB[j], shB[j]);
            p = __builtin_fmaf(gelu_f(v), w3B[j], p);
        }
        p += __shfl_xor(p, 1);
        p += __shfl_xor(p, 2);
        p += __shfl_xor(p, 4);
        if (cc == 0) out[(size_t)row * 28 + n] = p + b3n;
    }
}

// ------ pass 2 fallback (no h2 storage): full recompute ------------------
__global__ __launch_bounds__(256, 4) void k_pass2r(const float* __restrict__ g2,
                                                   const float* __restrict__ be2,
                                                   const float* __restrict__ W3,
                                                   const float* __restrict__ b3,
                                                   float* __restrict__ ws,
                                                   float* __restrict__ out) {
    __shared__ __align__(16) short sW1[64 * 40];
    __shared__ __align__(16) short sW2[64 * 72];
    __shared__ __align__(16) short sA1[8 * 16 * 72];
    __shared__ float sSc[64], sSh[64], sW3v[64];

    const int n = blockIdx.x >> 7;
    const int blk = blockIdx.x & 127;
    const int tid = threadIdx.x;
    const int wave = tid >> 6;
    const int lane = tid & 63;
    const int m = lane & 15;
    const int q = lane >> 4;

    const short* bfbase = (const short*)(ws + BF_BASE_F);
    const short* w1g = bfbase + (size_t)n * 64 * 32;
    const short* w2g = bfbase + W2B_OFF_S + (size_t)n * 64 * 64;
    const short* xbf = bfbase + XBF_OFF_S;
    {
        int r = tid >> 2, c = tid & 3;
        *(s8*)&sW1[r * 40 + c * 8] = *(const s8*)&w1g[r * 32 + c * 8];
#pragma unroll
        for (int k = 0; k < 2; ++k) {
            int i2x = tid + k * 256;
            int r2 = i2x >> 3, c2 = i2x & 7;
            *(s8*)&sW2[r2 * 72 + c2 * 8] = *(const s8*)&w2g[r2 * 64 + c2 * 8];
        }
        if (tid < 64) {
            float mean = ws[SUM2_OFF + n * 64 + tid] * (1.0f / 32768.0f);
            float var  = ws[SSQ2_OFF + n * 64 + tid] * (1.0f / 32768.0f) - mean * mean;
            float sc = g2[n * 64 + tid] * rsqrtf(fmaxf(var, 0.0f) + BN_EPS);
            sSc[tid]  = sc;
            sSh[tid]  = be2[n * 64 + tid] - mean * sc;
            sW3v[tid] = W3[n * 64 + tid];
        }
    }
    __syncthreads();

    const float* bias1 = ws + BIAS1_OFF + n * 64;
    const float b3n = b3[n];
    short* myA1a = &sA1[(wave * 2 + 0) * 16 * 72];
    short* myA1b = &sA1[(wave * 2 + 1) * 16 * 72];

#pragma unroll
    for (int it = 0; it < 2; ++it) {
        const int row0 = blk * 256 + it * 128 + wave * 32;
        s8 xfa = *(const s8*)&xbf[(size_t)(row0 + m) * 32 + 8 * q];
        s8 xfb = *(const s8*)&xbf[(size_t)(row0 + 16 + m) * 32 + 8 * q];

        f4 acc1a[4], acc1b[4];
#pragma unroll
        for (int t = 0; t < 4; ++t) {
            s8 wf = *(const s8*)&sW1[(16 * t + m) * 40 + q * 8];
            acc1a[t] = __builtin_amdgcn_mfma_f32_16x16x32_bf16(wf, xfa, (f4){0.f, 0.f, 0.f, 0.f}, 0, 0, 0);
            acc1b[t] = __builtin_amdgcn_mfma_f32_16x16x32_bf16(wf, xfb, (f4){0.f, 0.f, 0.f, 0.f}, 0, 0, 0);
        }
#pragma unroll
        for (int t = 0; t < 4; ++t) {
            f4 bv = *(const f4*)&bias1[16 * t + 4 * q];
            s4 pa, pb;
#pragma unroll
            for (int r = 0; r < 4; ++r) {
                pa[r] = (short)f2bf(gelu_f(acc1a[t][r] + bv[r]));
                pb[r] = (short)f2bf(gelu_f(acc1b[t][r] + bv[r]));
            }
            *(s4*)&myA1a[m * 72 + 16 * t + 4 * q] = pa;
            *(s4*)&myA1b[m * 72 + 16 * t + 4 * q] = pb;
        }
        s8 af0a = *(const s8*)&myA1a[m * 72 + 8 * q];
        s8 af1a = *(const s8*)&myA1a[m * 72 + 32 + 8 * q];
        s8 af0b = *(const s8*)&myA1b[m * 72 + 8 * q];
        s8 af1b = *(const s8*)&myA1b[m * 72 + 32 + 8 * q];
        float pa = 0.0f, pb = 0.0f;
#pragma unroll
        for (int u = 0; u < 4; ++u) {
            s8 w0 = *(const s8*)&sW2[(16 * u + m) * 72 + 8 * q];
            s8 w1 = *(const s8*)&sW2[(16 * u + m) * 72 + 32 + 8 * q];
            f4 aa = (f4){0.f, 0.f, 0.f, 0.f};
            f4 ab = (f4){0.f, 0.f, 0.f, 0.f};
            aa = __builtin_amdgcn_mfma_f32_16x16x32_bf16(w0, af0a, aa, 0, 0, 0);
            ab = __builtin_amdgcn_mfma_f32_16x16x32_bf16(w0, af0b, ab, 0, 0, 0);
            aa = __builtin_amdgcn_mfma_f32_16x16x32_bf16(w1, af1a, aa, 0, 0, 0);
            ab = __builtin_amdgcn_mfma_f32_16x16x32_bf16(w1, af1b, ab, 0, 0, 0);
            f4 scv = *(const f4*)&sSc[16 * u + 4 * q];
            f4 shv = *(const f4*)&sSh[16 * u + 4 * q];
            f4 w3v = *(const f4*)&sW3v[16 * u + 4 * q];
#pragma unroll
            for (int r = 0; r < 4; ++r) {
                float va = __builtin_fmaf(aa[r], scv[r], shv[r]);
                float vb = __builtin_fmaf(ab[r], scv[r], shv[r]);
                pa = __builtin_fmaf(gelu_f(va), w3v[r], pa);
                pb = __builtin_fmaf(gelu_f(vb), w3v[r], pb);
            }
        }
        pa += __shfl_xor(pa, 16);  pa += __shfl_xor(pa, 32);
        pb += __shfl_xor(pb, 16);  pb += __shfl_xor(pb, 32);
        if (q == 0) {
            out[(size_t)(row0 + m) * 28 + n]      = pa + b3n;
            out[(size_t)(row0 + 16 + m) * 28 + n] = pb + b3n;
        }
    }
}

extern "C" void kernel_launch(void* const* d_in, const int* in_sizes, int n_in,
                              void* d_out, int out_size, void* d_ws, size_t ws_size,
                              hipStream_t stream) {
    const float* X   = (const float*)d_in[0];
    const float* Wl  = (const float*)d_in[1];
    const float* W1  = (const float*)d_in[2];
    const float* g1  = (const float*)d_in[4];
    const float* be1 = (const float*)d_in[5];
    const float* W2  = (const float*)d_in[6];
    const float* g2  = (const float*)d_in[8];
    const float* be2 = (const float*)d_in[9];
    const float* W3  = (const float*)d_in[10];
    const float* b3  = (const float*)d_in[11];
    float* out = (float*)d_out;
    float* ws  = (float*)d_ws;
    short* h2buf = (short*)((char*)d_ws + H2_BYTE_OFF);
    const bool store_h2 = ws_size >= H2_BYTE_OFF + H2_BYTES;

    k_xstats<<<dim3(256), dim3(256), 0, stream>>>(X, ws);
    k_fold1<<<dim3(28), dim3(256), 0, stream>>>(Wl, W1, g1, be1, W2, ws, out + 917504);
    if (store_h2) {
        k_pass1<true><<<dim3(28 * 64), dim3(256), 0, stream>>>(ws, h2buf);
        k_pass2c<<<dim3(28 * 128), dim3(256), 0, stream>>>(g2, be2, W3, b3, ws, h2buf, out);
    } else {
        k_pass1<false><<<dim3(28 * 64), dim3(256), 0, stream>>>(ws, nullptr);
        k_pass2r<<<dim3(28 * 128), dim3(256), 0, stream>>>(g2, be2, W3, b3, ws, out);
    }
}

// Round 12
// 172.995 us; speedup vs baseline: 1.2775x; 1.2775x over previous
//
#include <hip/hip_runtime.h>
#include <hip/hip_bf16.h>
#include <math.h>

typedef float  f4 __attribute__((ext_vector_type(4)));
typedef short  s8 __attribute__((ext_vector_type(8)));
typedef short  s4 __attribute__((ext_vector_type(4)));
typedef int    i2 __attribute__((ext_vector_type(2)));

#define NV 28
#define NB 32768
#define BN_EPS 1e-5f
#define NSLOT 434   // 28 col-sums + 406 upper-tri Gram products

// ---- workspace layout (float indices unless noted) ----
#define SUM2_OFF   0        // 1792
#define SSQ2_OFF   1792     // 1792
#define BIAS1_OFF  3584     // 1792 -> 5376
#define PART_OFF   9472     // 256*434 -> 120576
#define BF_BASE_F  120640   // bf16 region; byte 482560 (16B aligned)
#define W2B_OFF_S  57344    // short offset of W2 bf16
#define XBF_OFF_S  172032   // short offset of padded bf16 X [32768][32]
#define H2_BYTE_OFF 2924544ull
#define H2_BYTES    117440512ull      // 28*32768*64*2

// fast gelu via hw exp2/rcp; max abs err ~5e-4
__device__ __forceinline__ float gelu_f(float x) {
    float x2 = x * x;
    float z  = x * __builtin_fmaf(x2, -0.10294324f, -2.3022082f);
    float t  = __builtin_amdgcn_exp2f(z);
    return x * __builtin_amdgcn_rcpf(1.0f + t);
}
// cheap round-to-nearest-even f32->bf16 (finite inputs)
__device__ __forceinline__ unsigned short f2bf(float x) {
    unsigned u = __builtin_bit_cast(unsigned, x);
    return (unsigned short)((u + 0x7fffu + ((u >> 16) & 1u)) >> 16);
}
__device__ __forceinline__ float bf2f(short s) {
    return __builtin_bit_cast(float, ((int)(unsigned short)s) << 16);
}
// pack two f32 -> two bf16 (round-nearest, ties-up) in 3 VALU ops via v_perm
__device__ __forceinline__ int bfpack(float a, float b) {
    unsigned ua = __builtin_bit_cast(unsigned, a) + 0x8000u;
    unsigned ub = __builtin_bit_cast(unsigned, b) + 0x8000u;
    return __builtin_amdgcn_perm(ub, ua, 0x07060302);  // lo16=bf16(a), hi16=bf16(b)
}
// sum across the 16 lanes of a DPP row; all lanes get the total
__device__ __forceinline__ float row16_sum(float v) {
    int x;
    x = __builtin_amdgcn_update_dpp(0, __builtin_bit_cast(int, v), 0xB1, 0xF, 0xF, true);
    v += __builtin_bit_cast(float, x);
    x = __builtin_amdgcn_update_dpp(0, __builtin_bit_cast(int, v), 0x4E, 0xF, 0xF, true);
    v += __builtin_bit_cast(float, x);
    x = __builtin_amdgcn_update_dpp(0, __builtin_bit_cast(int, v), 0x124, 0xF, 0xF, true);
    v += __builtin_bit_cast(float, x);
    x = __builtin_amdgcn_update_dpp(0, __builtin_bit_cast(int, v), 0x128, 0xF, 0xF, true);
    v += __builtin_bit_cast(float, x);
    return v;
}
// sum across a 4-lane quad; all 4 lanes get the total
__device__ __forceinline__ float quad4_sum(float v) {
    int x;
    x = __builtin_amdgcn_update_dpp(0, __builtin_bit_cast(int, v), 0xB1, 0xF, 0xF, true);
    v += __builtin_bit_cast(float, x);
    x = __builtin_amdgcn_update_dpp(0, __builtin_bit_cast(int, v), 0x4E, 0xF, 0xF, true);
    v += __builtin_bit_cast(float, x);
    return v;
}

// ------ X stats partials (upper-tri only) + bf16 pre-conversion of X -----
__global__ __launch_bounds__(256) void k_xstats(const float* __restrict__ X,
                                                float* __restrict__ ws) {
    __shared__ float sx[128 * 28];
    const int tid = threadIdx.x;
    const int rowbase = blockIdx.x * 128;
    {
        const f4* src = (const f4*)(X + (size_t)rowbase * 28);
        f4* dst = (f4*)sx;
        for (int i = tid; i < 128 * 28 / 4; i += 256) dst[i] = src[i];
    }
    __syncthreads();
    // bf16 X, padded to 32 cols (cols 28..31 zero)
    int* xb = (int*)((short*)(ws + BF_BASE_F) + XBF_OFF_S);
    for (int j = tid; j < 128 * 16; j += 256) {
        int row = j >> 4, cc = j & 15;
        float lo = (2 * cc     < 28) ? sx[row * 28 + 2 * cc]     : 0.0f;
        float hi = (2 * cc + 1 < 28) ? sx[row * 28 + 2 * cc + 1] : 0.0f;
        xb[(size_t)(rowbase + row) * 16 + cc] = (int)f2bf(lo) | ((int)f2bf(hi) << 16);
    }
    // slots: 0..27 col sums, 28.. upper-tri products (d<=e)
    for (int s = tid; s < NSLOT; s += 256) {
        float a = 0.0f;
        if (s < 28) {
            for (int r = 0; r < 128; ++r) a += sx[r * 28 + s];
        } else {
            int p = s - 28, d = 0, rem = 28;
            while (p >= rem) { p -= rem; ++d; --rem; }
            int e = d + p;
            for (int r = 0; r < 128; ++r)
                a = __builtin_fmaf(sx[r * 28 + d], sx[r * 28 + e], a);
        }
        ws[PART_OFF + blockIdx.x * NSLOT + s] = a;
    }
}

// ------ fold: reduce partials; sigmoid mask; analytic BN1 -> bf16 weights -
__global__ __launch_bounds__(256) void k_fold1(const float* __restrict__ Wlog,
                                               const float* __restrict__ W1,
                                               const float* __restrict__ g1,
                                               const float* __restrict__ be1,
                                               const float* __restrict__ W2,
                                               float* __restrict__ ws,
                                               float* __restrict__ out_w) {
    __shared__ float sstat[NSLOT];
    __shared__ float mu[28], wrow[28];
    __shared__ float C[784];
    __shared__ float w1e_s[64 * 28];
    const int n = blockIdx.x, t = threadIdx.x;

    // reduce the 256 xstats partials (strided; 16-deep load pipelining)
    for (int s = t; s < NSLOT; s += 256) {
        float a = 0.0f;
#pragma unroll 16
        for (int p = 0; p < 256; ++p) a += ws[PART_OFF + p * NSLOT + s];
        sstat[s] = a;
    }
    if (t < 64) {   // zero pass-1 stat accumulators for this mechanism
        ws[SUM2_OFF + n * 64 + t] = 0.0f;
        ws[SSQ2_OFF + n * 64 + t] = 0.0f;
    }
    __syncthreads();

    if (t < 28) {
        mu[t] = sstat[t] * (1.0f / 32768.0f);
        float w = 1.0f / (1.0f + expf(-Wlog[n * 28 + t]));
        if (t == n) w = 0.0f;
        wrow[t] = w;
        out_w[n * 28 + t] = w;          // second output: adjacency W
    }
    __syncthreads();
    // full covariance from upper-tri Gram: C = G/N - mu mu^T
    for (int i = t; i < 784; i += 256) {
        int d = i / 28, e = i % 28;
        int lo = d < e ? d : e, hi = d < e ? e : d;
        int idx = 28 + lo * 28 - (lo * (lo - 1)) / 2 + (hi - lo);
        C[i] = sstat[idx] * (1.0f / 32768.0f) - mu[d] * mu[e];
    }
    // masked first-layer weights for all 64 units (coalesced W1 reads)
    for (int i = t; i < 1792; i += 256)
        w1e_s[i] = W1[(size_t)n * 1792 + i] * wrow[i % 28];
    __syncthreads();

    const int h = t >> 2, j = t & 3;    // 4 lanes per hidden unit (one quad)
    const float* we = &w1e_s[h * 28];
    float var_p = 0.0f, dot_p = 0.0f;
#pragma unroll
    for (int k = 0; k < 7; ++k) {
        int d = 7 * j + k;
        float inner = 0.0f;
#pragma unroll
        for (int e = 0; e < 28; ++e) inner = __builtin_fmaf(C[d * 28 + e], we[e], inner);
        float wd = we[d];
        var_p = __builtin_fmaf(inner, wd, var_p);
        dot_p = __builtin_fmaf(wd, mu[d], dot_p);
    }
    float var  = quad4_sum(var_p);
    float dotm = quad4_sum(dot_p);
    float scale = g1[n * 64 + h] * rsqrtf(fmaxf(var, 0.0f) + BN_EPS);
    if (j == 0)
        ws[BIAS1_OFF + n * 64 + h] = be1[n * 64 + h] - dotm * scale;  // b1 cancels in BN

    short* bfbase = (short*)(ws + BF_BASE_F);
    {   // folded W1 bf16, padded to 32: lane j packs d in [8j, 8j+8)
        short* w1f = bfbase + (size_t)(n * 64 + h) * 32;
        s8 pk;
#pragma unroll
        for (int k = 0; k < 8; ++k) {
            int d = 8 * j + k;
            pk[k] = (short)f2bf(d < 28 ? we[d] * scale : 0.0f);
        }
        *(s8*)&w1f[8 * j] = pk;
    }
    {   // W2 -> bf16: 16 elements per thread, 16-B stores
        const float* w2src = W2 + (size_t)n * 4096 + t * 16;
        short* w2d = bfbase + W2B_OFF_S + (size_t)n * 4096 + t * 16;
        s8 a, b;
#pragma unroll
        for (int k = 0; k < 8; ++k) a[k] = (short)f2bf(w2src[k]);
#pragma unroll
        for (int k = 0; k < 8; ++k) b[k] = (short)f2bf(w2src[8 + k]);
        *(s8*)&w2d[0] = a;
        *(s8*)&w2d[8] = b;
    }
}

// ------ pass 1: GEMM1+gelu+GEMM2 (dual chains), reg stats, bf16 h2 store -
// proven config (r10, 48 us): launch_bounds(256,4), 256 rows/blk, 2-iter loop.
// Spill cliff: tighter bounds (r7/r8) OR 4-iter unroll (r11) both spill
// (WRITE_SIZE 204-270 MB vs 117 real). Do not change unroll depth or bounds.
template <bool STORE>
__global__ __launch_bounds__(256, 4) void k_pass1(float* __restrict__ ws,
                                                  short* __restrict__ h2buf) {
    __shared__ __align__(16) short sW1[64 * 40];
    __shared__ __align__(16) short sW2[64 * 72];
    __shared__ __align__(16) short sA1[8 * 16 * 72];     // 2 tiles per wave
    __shared__ float sP1[4][64], sP2[4][64];

    const int n = blockIdx.x >> 7;
    const int blk = blockIdx.x & 127;
    const int tid = threadIdx.x;
    const int wave = tid >> 6;
    const int lane = tid & 63;
    const int m = lane & 15;
    const int q = lane >> 4;

    const short* bfbase = (const short*)(ws + BF_BASE_F);
    const short* w1g = bfbase + (size_t)n * 64 * 32;
    const short* w2g = bfbase + W2B_OFF_S + (size_t)n * 64 * 64;
    const short* xbf = bfbase + XBF_OFF_S;
    {
        int r = tid >> 2, c = tid & 3;
        *(s8*)&sW1[r * 40 + c * 8] = *(const s8*)&w1g[r * 32 + c * 8];
#pragma unroll
        for (int k = 0; k < 2; ++k) {
            int i2x = tid + k * 256;
            int r2 = i2x >> 3, c2 = i2x & 7;
            *(s8*)&sW2[r2 * 72 + c2 * 8] = *(const s8*)&w2g[r2 * 64 + c2 * 8];
        }
    }
    __syncthreads();

    // lane-constant bias fragments hoisted (16 VGPRs; ample headroom at bound 4)
    const float* bias1 = ws + BIAS1_OFF + n * 64;
    f4 biasv[4];
#pragma unroll
    for (int t = 0; t < 4; ++t) biasv[t] = *(const f4*)&bias1[16 * t + 4 * q];

    short* myA1a = &sA1[(wave * 2 + 0) * 16 * 72];
    short* myA1b = &sA1[(wave * 2 + 1) * 16 * 72];
    float s1[16], s2v[16];
#pragma unroll
    for (int i = 0; i < 16; ++i) { s1[i] = 0.0f; s2v[i] = 0.0f; }

#pragma unroll
    for (int it = 0; it < 2; ++it) {
        const int row0 = blk * 256 + it * 128 + wave * 32;
        s8 xfa = *(const s8*)&xbf[(size_t)(row0 + m) * 32 + 8 * q];
        s8 xfb = *(const s8*)&xbf[(size_t)(row0 + 16 + m) * 32 + 8 * q];

        f4 acc1a[4], acc1b[4];
#pragma unroll
        for (int t = 0; t < 4; ++t) {
            s8 wf = *(const s8*)&sW1[(16 * t + m) * 40 + q * 8];
            acc1a[t] = __builtin_amdgcn_mfma_f32_16x16x32_bf16(wf, xfa, (f4){0.f, 0.f, 0.f, 0.f}, 0, 0, 0);
            acc1b[t] = __builtin_amdgcn_mfma_f32_16x16x32_bf16(wf, xfb, (f4){0.f, 0.f, 0.f, 0.f}, 0, 0, 0);
        }
#pragma unroll
        for (int t = 0; t < 4; ++t) {
            float ga0 = gelu_f(acc1a[t][0] + biasv[t][0]);
            float ga1 = gelu_f(acc1a[t][1] + biasv[t][1]);
            float ga2 = gelu_f(acc1a[t][2] + biasv[t][2]);
            float ga3 = gelu_f(acc1a[t][3] + biasv[t][3]);
            float gb0 = gelu_f(acc1b[t][0] + biasv[t][0]);
            float gb1 = gelu_f(acc1b[t][1] + biasv[t][1]);
            float gb2 = gelu_f(acc1b[t][2] + biasv[t][2]);
            float gb3 = gelu_f(acc1b[t][3] + biasv[t][3]);
            i2 pa = (i2){bfpack(ga0, ga1), bfpack(ga2, ga3)};
            i2 pb = (i2){bfpack(gb0, gb1), bfpack(gb2, gb3)};
            *(i2*)&myA1a[m * 72 + 16 * t + 4 * q] = pa;
            *(i2*)&myA1b[m * 72 + 16 * t + 4 * q] = pb;
        }
        // in-wave LDS ordering only; sA1 tiles are wave-private
        s8 af0a = *(const s8*)&myA1a[m * 72 + 8 * q];
        s8 af1a = *(const s8*)&myA1a[m * 72 + 32 + 8 * q];
        s8 af0b = *(const s8*)&myA1b[m * 72 + 8 * q];
        s8 af1b = *(const s8*)&myA1b[m * 72 + 32 + 8 * q];
        short* hpA = STORE ? (h2buf + ((size_t)n * NB + row0 + m) * 64) : nullptr;
        short* hpB = STORE ? (h2buf + ((size_t)n * NB + row0 + 16 + m) * 64) : nullptr;
#pragma unroll
        for (int u = 0; u < 4; ++u) {
            s8 w0 = *(const s8*)&sW2[(16 * u + m) * 72 + 8 * q];
            s8 w1 = *(const s8*)&sW2[(16 * u + m) * 72 + 32 + 8 * q];
            f4 aa = (f4){0.f, 0.f, 0.f, 0.f};
            f4 ab = (f4){0.f, 0.f, 0.f, 0.f};
            aa = __builtin_amdgcn_mfma_f32_16x16x32_bf16(w0, af0a, aa, 0, 0, 0);
            ab = __builtin_amdgcn_mfma_f32_16x16x32_bf16(w0, af0b, ab, 0, 0, 0);
            aa = __builtin_amdgcn_mfma_f32_16x16x32_bf16(w1, af1a, aa, 0, 0, 0);
            ab = __builtin_amdgcn_mfma_f32_16x16x32_bf16(w1, af1b, ab, 0, 0, 0);
            if (STORE) {
                i2 ha = (i2){bfpack(aa[0], aa[1]), bfpack(aa[2], aa[3])};
                i2 hb = (i2){bfpack(ab[0], ab[1]), bfpack(ab[2], ab[3])};
                *(i2*)&hpA[16 * u + 4 * q] = ha;
                *(i2*)&hpB[16 * u + 4 * q] = hb;
            }
#pragma unroll
            for (int r = 0; r < 4; ++r) {
                s1[u * 4 + r]  += aa[r] + ab[r];
                s2v[u * 4 + r] = __builtin_fmaf(aa[r], aa[r], s2v[u * 4 + r]);
                s2v[u * 4 + r] = __builtin_fmaf(ab[r], ab[r], s2v[u * 4 + r]);
            }
        }
    }
    // block-level reduction via LDS (short live ranges; no spill)
#pragma unroll
    for (int u = 0; u < 4; ++u) {
#pragma unroll
        for (int r = 0; r < 4; ++r) {
            float t1 = row16_sum(s1[u * 4 + r]);
            float t2 = row16_sum(s2v[u * 4 + r]);
            if (m == 0) {
                sP1[wave][16 * u + 4 * q + r] = t1;
                sP2[wave][16 * u + 4 * q + r] = t2;
            }
        }
    }
    __syncthreads();
    if (tid < 64) {
        float a = sP1[0][tid] + sP1[1][tid] + sP1[2][tid] + sP1[3][tid];
        float b = sP2[0][tid] + sP2[1][tid] + sP2[2][tid] + sP2[3][tid];
        atomicAdd(&ws[SUM2_OFF + n * 64 + tid], a);
        atomicAdd(&ws[SSQ2_OFF + n * 64 + tid], b);
    }
}

// ------ pass 2 (stored h2, coalesced): BN2+gelu+GEMM3 -> X_hat -----------
// 8 lanes per row: wave loads 1 KB contiguous; 3-step shuffle reduce.
__global__ __launch_bounds__(256) void k_pass2c(const float* __restrict__ g2,
                                                const float* __restrict__ be2,
                                                const float* __restrict__ W3,
                                                const float* __restrict__ b3,
                                                const float* __restrict__ ws,
                                                const short* __restrict__ h2buf,
                                                float* __restrict__ out) {
    __shared__ float sSc[64], sSh[64], sW3v[64];
    const int n = blockIdx.x >> 8;
    const int rbase = (blockIdx.x & 255) * 128;
    const int tid = threadIdx.x;
    if (tid < 64) {
        float mean = ws[SUM2_OFF + n * 64 + tid] * (1.0f / 32768.0f);
        float var  = ws[SSQ2_OFF + n * 64 + tid] * (1.0f / 32768.0f) - mean * mean;
        float sc = g2[n * 64 + tid] * rsqrtf(fmaxf(var, 0.0f) + BN_EPS);
        sSc[tid]  = sc;
        sSh[tid]  = be2[n * 64 + tid] - mean * sc;
        sW3v[tid] = W3[n * 64 + tid];
    }
    __syncthreads();
    const int wave = tid >> 6;
    const int lane = tid & 63;
    const int rr = lane >> 3;          // row within 8-row group
    const int cc = lane & 7;           // 8-feature chunk within row
    // per-lane feature params in registers (shared across all rows)
    f4 scA = *(const f4*)&sSc[cc * 8],     scB = *(const f4*)&sSc[cc * 8 + 4];
    f4 shA = *(const f4*)&sSh[cc * 8],     shB = *(const f4*)&sSh[cc * 8 + 4];
    f4 w3A = *(const f4*)&sW3v[cc * 8],    w3B = *(const f4*)&sW3v[cc * 8 + 4];
    const float b3n = b3[n];
#pragma unroll
    for (int it = 0; it < 4; ++it) {
        const int row = rbase + wave * 32 + it * 8 + rr;
        s8 hv = *(const s8*)(h2buf + ((size_t)n * NB + row) * 64 + cc * 8);
        float p = 0.0f;
#pragma unroll
        for (int j = 0; j < 4; ++j) {
            float v = __builtin_fmaf(bf2f(hv[j]), scA[j], shA[j]);
            p = __builtin_fmaf(gelu_f(v), w3A[j], p);
        }
#pragma unroll
        for (int j = 0; j < 4; ++j) {
            float v = __builtin_fmaf(bf2f(hv[4 + j]), scB[j], shB[j]);
            p = __builtin_fmaf(gelu_f(v), w3B[j], p);
        }
        p += __shfl_xor(p, 1);
        p += __shfl_xor(p, 2);
        p += __shfl_xor(p, 4);
        if (cc == 0) out[(size_t)row * 28 + n] = p + b3n;
    }
}

// ------ pass 2 fallback (no h2 storage): full recompute ------------------
__global__ __launch_bounds__(256, 4) void k_pass2r(const float* __restrict__ g2,
                                                   const float* __restrict__ be2,
                                                   const float* __restrict__ W3,
                                                   const float* __restrict__ b3,
                                                   float* __restrict__ ws,
                                                   float* __restrict__ out) {
    __shared__ __align__(16) short sW1[64 * 40];
    __shared__ __align__(16) short sW2[64 * 72];
    __shared__ __align__(16) short sA1[8 * 16 * 72];
    __shared__ float sSc[64], sSh[64], sW3v[64];

    const int n = blockIdx.x >> 7;
    const int blk = blockIdx.x & 127;
    const int tid = threadIdx.x;
    const int wave = tid >> 6;
    const int lane = tid & 63;
    const int m = lane & 15;
    const int q = lane >> 4;

    const short* bfbase = (const short*)(ws + BF_BASE_F);
    const short* w1g = bfbase + (size_t)n * 64 * 32;
    const short* w2g = bfbase + W2B_OFF_S + (size_t)n * 64 * 64;
    const short* xbf = bfbase + XBF_OFF_S;
    {
        int r = tid >> 2, c = tid & 3;
        *(s8*)&sW1[r * 40 + c * 8] = *(const s8*)&w1g[r * 32 + c * 8];
#pragma unroll
        for (int k = 0; k < 2; ++k) {
            int i2x = tid + k * 256;
            int r2 = i2x >> 3, c2 = i2x & 7;
            *(s8*)&sW2[r2 * 72 + c2 * 8] = *(const s8*)&w2g[r2 * 64 + c2 * 8];
        }
        if (tid < 64) {
            float mean = ws[SUM2_OFF + n * 64 + tid] * (1.0f / 32768.0f);
            float var  = ws[SSQ2_OFF + n * 64 + tid] * (1.0f / 32768.0f) - mean * mean;
            float sc = g2[n * 64 + tid] * rsqrtf(fmaxf(var, 0.0f) + BN_EPS);
            sSc[tid]  = sc;
            sSh[tid]  = be2[n * 64 + tid] - mean * sc;
            sW3v[tid] = W3[n * 64 + tid];
        }
    }
    __syncthreads();

    const float* bias1 = ws + BIAS1_OFF + n * 64;
    const float b3n = b3[n];
    short* myA1a = &sA1[(wave * 2 + 0) * 16 * 72];
    short* myA1b = &sA1[(wave * 2 + 1) * 16 * 72];

#pragma unroll
    for (int it = 0; it < 2; ++it) {
        const int row0 = blk * 256 + it * 128 + wave * 32;
        s8 xfa = *(const s8*)&xbf[(size_t)(row0 + m) * 32 + 8 * q];
        s8 xfb = *(const s8*)&xbf[(size_t)(row0 + 16 + m) * 32 + 8 * q];

        f4 acc1a[4], acc1b[4];
#pragma unroll
        for (int t = 0; t < 4; ++t) {
            s8 wf = *(const s8*)&sW1[(16 * t + m) * 40 + q * 8];
            acc1a[t] = __builtin_amdgcn_mfma_f32_16x16x32_bf16(wf, xfa, (f4){0.f, 0.f, 0.f, 0.f}, 0, 0, 0);
            acc1b[t] = __builtin_amdgcn_mfma_f32_16x16x32_bf16(wf, xfb, (f4){0.f, 0.f, 0.f, 0.f}, 0, 0, 0);
        }
#pragma unroll
        for (int t = 0; t < 4; ++t) {
            f4 bv = *(const f4*)&bias1[16 * t + 4 * q];
            s4 pa, pb;
#pragma unroll
            for (int r = 0; r < 4; ++r) {
                pa[r] = (short)f2bf(gelu_f(acc1a[t][r] + bv[r]));
                pb[r] = (short)f2bf(gelu_f(acc1b[t][r] + bv[r]));
            }
            *(s4*)&myA1a[m * 72 + 16 * t + 4 * q] = pa;
            *(s4*)&myA1b[m * 72 + 16 * t + 4 * q] = pb;
        }
        s8 af0a = *(const s8*)&myA1a[m * 72 + 8 * q];
        s8 af1a = *(const s8*)&myA1a[m * 72 + 32 + 8 * q];
        s8 af0b = *(const s8*)&myA1b[m * 72 + 8 * q];
        s8 af1b = *(const s8*)&myA1b[m * 72 + 32 + 8 * q];
        float pa = 0.0f, pb = 0.0f;
#pragma unroll
        for (int u = 0; u < 4; ++u) {
            s8 w0 = *(const s8*)&sW2[(16 * u + m) * 72 + 8 * q];
            s8 w1 = *(const s8*)&sW2[(16 * u + m) * 72 + 32 + 8 * q];
            f4 aa = (f4){0.f, 0.f, 0.f, 0.f};
            f4 ab = (f4){0.f, 0.f, 0.f, 0.f};
            aa = __builtin_amdgcn_mfma_f32_16x16x32_bf16(w0, af0a, aa, 0, 0, 0);
            ab = __builtin_amdgcn_mfma_f32_16x16x32_bf16(w0, af0b, ab, 0, 0, 0);
            aa = __builtin_amdgcn_mfma_f32_16x16x32_bf16(w1, af1a, aa, 0, 0, 0);
            ab = __builtin_amdgcn_mfma_f32_16x16x32_bf16(w1, af1b, ab, 0, 0, 0);
            f4 scv = *(const f4*)&sSc[16 * u + 4 * q];
            f4 shv = *(const f4*)&sSh[16 * u + 4 * q];
            f4 w3v = *(const f4*)&sW3v[16 * u + 4 * q];
#pragma unroll
            for (int r = 0; r < 4; ++r) {
                float va = __builtin_fmaf(aa[r], scv[r], shv[r]);
                float vb = __builtin_fmaf(ab[r], scv[r], shv[r]);
                pa = __builtin_fmaf(gelu_f(va), w3v[r], pa);
                pb = __builtin_fmaf(gelu_f(vb), w3v[r], pb);
            }
        }
        pa += __shfl_xor(pa, 16);  pa += __shfl_xor(pa, 32);
        pb += __shfl_xor(pb, 16);  pb += __shfl_xor(pb, 32);
        if (q == 0) {
            out[(size_t)(row0 + m) * 28 + n]      = pa + b3n;
            out[(size_t)(row0 + 16 + m) * 28 + n] = pb + b3n;
        }
    }
}

extern "C" void kernel_launch(void* const* d_in, const int* in_sizes, int n_in,
                              void* d_out, int out_size, void* d_ws, size_t ws_size,
                              hipStream_t stream) {
    const float* X   = (const float*)d_in[0];
    const float* Wl  = (const float*)d_in[1];
    const float* W1  = (const float*)d_in[2];
    const float* g1  = (const float*)d_in[4];
    const float* be1 = (const float*)d_in[5];
    const float* W2  = (const float*)d_in[6];
    const float* g2  = (const float*)d_in[8];
    const float* be2 = (const float*)d_in[9];
    const float* W3  = (const float*)d_in[10];
    const float* b3  = (const float*)d_in[11];
    float* out = (float*)d_out;
    float* ws  = (float*)d_ws;
    short* h2buf = (short*)((char*)d_ws + H2_BYTE_OFF);
    const bool store_h2 = ws_size >= H2_BYTE_OFF + H2_BYTES;

    k_xstats<<<dim3(256), dim3(256), 0, stream>>>(X, ws);
    k_fold1<<<dim3(28), dim3(256), 0, stream>>>(Wl, W1, g1, be1, W2, ws, out + 917504);
    if (store_h2) {
        k_pass1<true><<<dim3(28 * 128), dim3(256), 0, stream>>>(ws, h2buf);
        k_pass2c<<<dim3(28 * 256), dim3(256), 0, stream>>>(g2, be2, W3, b3, ws, h2buf, out);
    } else {
        k_pass1<false><<<dim3(28 * 128), dim3(256), 0, stream>>>(ws, nullptr);
        k_pass2r<<<dim3(28 * 128), dim3(256), 0, stream>>>(g2, be2, W3, b3, ws, out);
    }
}